// Round 7
// baseline (152.105 us; speedup 1.0000x reference)
//
#include <hip/hip_runtime.h>
#include <cstdint>
#include <cstddef>

#define N_NODES 8192
#define IN_DIM 128
#define H 32
#define KB 8192          // path-2 buckets
#define NCH 66           // 32 E*Wh + 32 F*Wh + E + F channels

typedef __attribute__((ext_vector_type(8))) short short8;
typedef __attribute__((ext_vector_type(4))) float f32x4;

__device__ __forceinline__ float sigmoidf_(float x) { return 1.0f / (1.0f + __expf(-x)); }
__device__ __forceinline__ float tanh_fast(float x) { return 1.0f - 2.0f / (1.0f + __expf(2.0f * x)); }
__device__ __forceinline__ unsigned short f2bf(float f) {
    unsigned u = __float_as_uint(f);
    unsigned r = (u + 0x7fffu + ((u >> 16) & 1u)) >> 16;
    return (unsigned short)r;
}
// pack two f32 -> one u32 of 2 bf16 (lo|hi<<16), round-to-nearest (ties down)
__device__ __forceinline__ unsigned pack_bf_pair(float lo, float hi) {
    unsigned a = __float_as_uint(lo) + 0x7FFFu;
    unsigned b = __float_as_uint(hi) + 0x7FFFu;
    return __builtin_amdgcn_perm(b, a, 0x07060302u);
}

// ---------------------------------------------------------------------------
// K1: Wh = x@W^T + b for both paths. Path1 -> WhTf: bf16 B-fragment layout
//   off = [T=j>>7][hg=h>>4][ks=(j>>5)&3][lane=(h&15)|(((j>>3)&3)<<4)][e=j&7]
// so k2 waves load B-fragments as coalesced 1KB chunks. Path2 -> Wh2f f32.
// s = Wh@a. Also zeroes Sc.
// ---------------------------------------------------------------------------
__global__ __launch_bounds__(256) void k1_wh_s(
    const float* __restrict__ x,
    const float* __restrict__ W1, const float* __restrict__ b1, const float* __restrict__ a1,
    const float* __restrict__ W2, const float* __restrict__ b2, const float* __restrict__ a2,
    unsigned short* __restrict__ WhTf, float* __restrict__ Wh2f,
    float* __restrict__ s1, float* __restrict__ s2, float* __restrict__ Sc)
{
    __shared__ float xl[8 * IN_DIM];
    int tid = threadIdx.x;
    int row0 = blockIdx.x * 8;

    // zero Sc: 66*8192 floats = 135168 float4 over 1024 blocks x 256 thr
    {
        int idx = blockIdx.x * 256 + tid;
        if (idx < (NCH * KB) / 4)
            ((float4*)Sc)[idx] = make_float4(0.f, 0.f, 0.f, 0.f);
    }

    ((float4*)xl)[tid] = ((const float4*)(x + (size_t)row0 * IN_DIM))[tid];
    __syncthreads();

    int r = tid >> 5, h = tid & 31;
    const float* xr = xl + r * IN_DIM;
    const float* w1r = W1 + h * IN_DIM;
    const float* w2r = W2 + h * IN_DIM;
    float d1 = 0.f, d2 = 0.f;
#pragma unroll 8
    for (int k = 0; k < IN_DIM; k += 4) {
        float4 xv = *(const float4*)(xr + k);
        float4 wa = *(const float4*)(w1r + k);
        float4 wb = *(const float4*)(w2r + k);
        d1 += xv.x * wa.x + xv.y * wa.y + xv.z * wa.z + xv.w * wa.w;
        d2 += xv.x * wb.x + xv.y * wb.y + xv.z * wb.z + xv.w * wb.w;
    }
    int grow = row0 + r;
    float wh1 = d1 + b1[h];
    float wh2 = d2 + b2[h];

    // fragment-layout scatter store of bf16 Wh1
    {
        int T  = grow >> 7;
        int kk = grow & 127;
        int ks = kk >> 5;
        int kg = (kk >> 3) & 3;
        int e  = kk & 7;
        int ln = (h & 15) | (kg << 4);
        size_t off = ((size_t)((T * 2 + (h >> 4)) * 4 + ks) << 9) + (size_t)ln * 8 + e;
        WhTf[off] = f2bf(wh1);
    }
    Wh2f[(size_t)grow * H + h] = wh2;

    float v1 = wh1 * a1[h];
    float v2 = wh2 * a2[h];
#pragma unroll
    for (int m = 16; m >= 1; m >>= 1) { v1 += __shfl_xor(v1, m); v2 += __shfl_xor(v2, m); }
    if (h == 0) { s1[grow] = v1; s2[grow] = v2; }
}

// ---------------------------------------------------------------------------
// K1b: M[0]=max(s1), M[1]=max(s2), M[2]=min(s2)
// ---------------------------------------------------------------------------
__global__ __launch_bounds__(256) void k1b_max(
    const float* __restrict__ s1, const float* __restrict__ s2, float* __restrict__ M)
{
    int tid = threadIdx.x;
    float m1 = -1e30f, m2 = -1e30f, n2 = 1e30f;
    for (int i = tid; i < N_NODES; i += 256) {
        m1 = fmaxf(m1, s1[i]);
        float v = s2[i];
        m2 = fmaxf(m2, v);
        n2 = fminf(n2, v);
    }
#pragma unroll
    for (int m = 32; m >= 1; m >>= 1) {
        m1 = fmaxf(m1, __shfl_xor(m1, m));
        m2 = fmaxf(m2, __shfl_xor(m2, m));
        n2 = fminf(n2, __shfl_xor(n2, m));
    }
    __shared__ float red[12];
    if ((tid & 63) == 0) {
        int w = tid >> 6;
        red[w * 3] = m1; red[w * 3 + 1] = m2; red[w * 3 + 2] = n2;
    }
    __syncthreads();
    if (tid == 0) {
        float a = red[0], b = red[1], c = red[2];
        for (int w = 1; w < 4; ++w) {
            a = fmaxf(a, red[w * 3]);
            b = fmaxf(b, red[w * 3 + 1]);
            c = fminf(c, red[w * 3 + 2]);
        }
        M[0] = a; M[1] = b; M[2] = c;
    }
}

// ---------------------------------------------------------------------------
// P2a: bucket-accumulate path 2. grid 1024 x 256 (8 j x 32 h)
// ---------------------------------------------------------------------------
__global__ __launch_bounds__(256) void p2a_bucket(
    const float* __restrict__ s2, const float* __restrict__ Wh2f,
    const float* __restrict__ M, float* __restrict__ Sc)
{
    int tid = threadIdx.x;
    int j = blockIdx.x * 8 + (tid >> 5);
    int h = tid & 31;
    float M1 = M[1], lo = M[2];
    float invw = (float)KB / fmaxf(M1 - lo, 1e-9f);
    float sv = s2[j];
    int b = (int)((sv - lo) * invw);
    b = min(max(b, 0), KB - 1);
    float E = __expf(sv - M1);
    float F = __expf(0.2f * (sv - M1));
    float wh = Wh2f[(size_t)j * H + h];
    atomicAdd(&Sc[(size_t)h * KB + b], E * wh);
    atomicAdd(&Sc[(size_t)(32 + h) * KB + b], F * wh);
    if (h == 0) {
        atomicAdd(&Sc[(size_t)64 * KB + b], E);
        atomicAdd(&Sc[(size_t)65 * KB + b], F);
    }
}

// ---------------------------------------------------------------------------
// P2b: full-channel suffix-inclusive scan in place. grid 66 x 256.
// ---------------------------------------------------------------------------
__global__ __launch_bounds__(256) void p2b_scan(float* __restrict__ Sc)
{
    int ch = blockIdx.x;
    float* chb = Sc + (size_t)ch * KB;
    int tid = threadIdx.x;
    int lane = tid & 63;
    __shared__ float wt[4];
    __shared__ float sCarry;
    float carry = 0.f;

    for (int chunk = 7; chunk >= 0; --chunk) {
        float* base = chb + chunk * 1024;
        int k0 = tid * 4;
        float x0 = base[1023 - k0];
        float x1 = base[1022 - k0];
        float x2 = base[1021 - k0];
        float x3 = base[1020 - k0];
        float p1 = x0 + x1, p2 = p1 + x2, p3 = p2 + x3;
        float inc = p3;
#pragma unroll
        for (int d = 1; d < 64; d <<= 1) {
            float y = __shfl_up(inc, d);
            if (lane >= d) inc += y;
        }
        if (lane == 63) wt[tid >> 6] = inc;
        __syncthreads();
        int wv = tid >> 6;
        float woff = carry;
        if (wv > 0) woff += wt[0];
        if (wv > 1) woff += wt[1];
        if (wv > 2) woff += wt[2];
        float offv = woff + (inc - p3);
        base[1023 - k0] = x0 + offv;
        base[1022 - k0] = p1 + offv;
        base[1021 - k0] = p2 + offv;
        base[1020 - k0] = p3 + offv;
        if (tid == 255) sCarry = p3 + offv;
        __syncthreads();
        carry = sCarry;
    }
}

// ---------------------------------------------------------------------------
// K2: path-1 MFMA attention. B-fragments loaded straight from WhTf global
// (pre-swizzled, coalesced, register double-buffered). Only the computed
// w-tile lives in LDS (double-buffered, XOR-swizzled). One barrier/tile.
// Issue order per iter: sj(1), Bn(4), adjN(4) -> consumers never force a
// drain of younger prefetches (ordered-vmcnt discipline).
// ---------------------------------------------------------------------------
__global__ __launch_bounds__(512, 4) void k2_attn1(
    const float* __restrict__ s1g, const unsigned short* __restrict__ WhTf,
    const int* __restrict__ adj, const float* __restrict__ M,
    float* __restrict__ num1, float* __restrict__ den1)
{
    __shared__ unsigned short w_lds[2][64 * 128];   // 2 x 16 KB, XOR-swizzled
    __shared__ float srow[64], g1r[64], g2r[64];

    int tid = threadIdx.x;
    int row0 = blockIdx.x * 64;
    int jb = blockIdx.y;
    int jstart = jb * 2048;
    float M0 = M[0];

    if (tid < 64) {
        float sv = s1g[row0 + tid];
        srow[tid] = sv;
        float u = sv + M0;
        g1r[tid] = u >= 0.f ? 1.f : __expf(0.8f * u);
        g2r[tid] = u >= 0.f ? __expf(-0.8f * u) : 1.f;
    }
    __syncthreads();

    int wave = tid >> 6;
    int lane = tid & 63;
    int rg = wave >> 1;        // row group 0..3
    int hg = wave & 1;         // h group 0..1
    int grp = lane >> 4;

    int arow = rg * 16 + (lane & 15);
    int aswz = (arow & 7) << 4;
    int a_base = arow * 256;

    // B-fragment base for this wave: WhTf[(T*2+hg)*4 + ks][lane][8]
    const unsigned short* bf_base = WhTf + (size_t)lane * 8 + (size_t)hg * 2048;

    int tcol = (tid & 31) * 4;
    int trh = tid >> 5;                // 0..15
    const int* adjb = adj + (size_t)row0 * N_NODES + tcol;

    f32x4 acc1 = {0.f, 0.f, 0.f, 0.f};
    float l0 = 0.f, l1 = 0.f, l2 = 0.f, l3 = 0.f;

    int4 cA, cB, cC, cD, nA, nB, nC, nD;
    short8 Bc0, Bc1, Bc2, Bc3, Bn0, Bn1, Bn2, Bn3;
    float4 sj, e4, f4;

#define W_GEN(KK, AV, LL, WB)                                                   \
        {                                                                       \
            int r = KK * 16 + trh;                                              \
            float sr = srow[r], g1v = g1r[r], g2v = g2r[r];                     \
            bool px = sr + sj.x >= 0.f, py = sr + sj.y >= 0.f;                  \
            bool pz = sr + sj.z >= 0.f, pw = sr + sj.w >= 0.f;                  \
            float wx = (px ? g1v : g2v) * (px ? e4.x : f4.x);                   \
            float wy = (py ? g1v : g2v) * (py ? e4.y : f4.y);                   \
            float wz = (pz ? g1v : g2v) * (pz ? e4.z : f4.z);                   \
            float ww = (pw ? g1v : g2v) * (pw ? e4.w : f4.w);                   \
            if (AV.x == 0) wx = 0.f;                                            \
            if (AV.y == 0) wy = 0.f;                                            \
            if (AV.z == 0) wz = 0.f;                                            \
            if (AV.w == 0) ww = 0.f;                                            \
            LL += (wx + wy) + (wz + ww);                                        \
            uint2 pk;                                                           \
            pk.x = pack_bf_pair(wx, wy);                                        \
            pk.y = pack_bf_pair(wz, ww);                                        \
            int byte = (r * 256 + tcol * 2) ^ ((r & 7) << 4);                   \
            *(uint2*)((char*)(WB) + byte) = pk;                                 \
        }

#define SJ_LOAD(J0)  sj = *(const float4*)(s1g + (J0) + tcol);

#define EF_GEN()                                                                \
        {                                                                       \
            e4.x = __expf(sj.x - M0); e4.y = __expf(sj.y - M0);                 \
            e4.z = __expf(sj.z - M0); e4.w = __expf(sj.w - M0);                 \
            f4.x = __expf(0.2f * (sj.x - M0)); f4.y = __expf(0.2f * (sj.y - M0)); \
            f4.z = __expf(0.2f * (sj.z - M0)); f4.w = __expf(0.2f * (sj.w - M0)); \
        }

#define ADJ_LOAD(DA, DB, DC, DD, J0)                                            \
        {                                                                       \
            DA = *(const int4*)(adjb + (size_t)(0 * 16 + trh) * N_NODES + (J0)); \
            DB = *(const int4*)(adjb + (size_t)(1 * 16 + trh) * N_NODES + (J0)); \
            DC = *(const int4*)(adjb + (size_t)(2 * 16 + trh) * N_NODES + (J0)); \
            DD = *(const int4*)(adjb + (size_t)(3 * 16 + trh) * N_NODES + (J0)); \
        }

#define BF_LOAD(B0, B1, B2, B3, T)                                              \
        {                                                                       \
            const unsigned short* p = bf_base + ((size_t)(T) << 12);            \
            B0 = *(const short8*)(p);                                           \
            B1 = *(const short8*)(p + 512);                                     \
            B2 = *(const short8*)(p + 1024);                                    \
            B3 = *(const short8*)(p + 1536);                                    \
        }

    int T0 = jb * 16;

    // ---- prologue: tile 0 fully staged; adjacency tile 1 prefetched ----
    SJ_LOAD(jstart)
    BF_LOAD(Bc0, Bc1, Bc2, Bc3, T0)
    ADJ_LOAD(cA, cB, cC, cD, jstart)
    ADJ_LOAD(nA, nB, nC, nD, jstart + 128)
    EF_GEN()
    W_GEN(0, cA, l0, w_lds[0])
    W_GEN(1, cB, l1, w_lds[0])
    W_GEN(2, cC, l2, w_lds[0])
    W_GEN(3, cD, l3, w_lds[0])
    cA = nA; cB = nB; cC = nC; cD = nD;   // cX now holds tile jt+1's adjacency

    int cur = 0;
    for (int jt = 0; jt < 16; ++jt) {
        __syncthreads();           // w_lds[cur] (tile jt) ready
        int nb = cur ^ 1;

        // issue younger->older consumer order: sj, Bfrags, adj
        if (jt < 15) {
            SJ_LOAD(jstart + (jt + 1) * 128)
            BF_LOAD(Bn0, Bn1, Bn2, Bn3, T0 + jt + 1)
        }
        if (jt < 14) {
            ADJ_LOAD(nA, nB, nC, nD, jstart + (jt + 2) * 128)
        }

        // MFMA on tile jt: A from w_lds[cur], B from registers (drained)
        {
            const char* wb = (const char*)w_lds[cur];
            short8 a0 = *(const short8*)(wb + ((a_base + 0 * 64 + grp * 16) ^ aswz));
            acc1 = __builtin_amdgcn_mfma_f32_16x16x32_bf16(a0, Bc0, acc1, 0, 0, 0);
            short8 a1 = *(const short8*)(wb + ((a_base + 1 * 64 + grp * 16) ^ aswz));
            acc1 = __builtin_amdgcn_mfma_f32_16x16x32_bf16(a1, Bc1, acc1, 0, 0, 0);
            short8 a2 = *(const short8*)(wb + ((a_base + 2 * 64 + grp * 16) ^ aswz));
            acc1 = __builtin_amdgcn_mfma_f32_16x16x32_bf16(a2, Bc2, acc1, 0, 0, 0);
            short8 a3 = *(const short8*)(wb + ((a_base + 3 * 64 + grp * 16) ^ aswz));
            acc1 = __builtin_amdgcn_mfma_f32_16x16x32_bf16(a3, Bc3, acc1, 0, 0, 0);
        }

        if (jt < 15) {
            EF_GEN()               // waits sj only; Bn/adjN stay in flight
            W_GEN(0, cA, l0, w_lds[nb])
            W_GEN(1, cB, l1, w_lds[nb])
            W_GEN(2, cC, l2, w_lds[nb])
            W_GEN(3, cD, l3, w_lds[nb])
            Bc0 = Bn0; Bc1 = Bn1; Bc2 = Bn2; Bc3 = Bn3;
            if (jt < 14) { cA = nA; cB = nB; cC = nC; cD = nD; }
        }
        cur = nb;
    }
#undef W_GEN
#undef SJ_LOAD
#undef EF_GEN
#undef ADJ_LOAD
#undef BF_LOAD

    // numerators: C/D layout col=lane&15 (h), row=(lane>>4)*4+reg
#pragma unroll
    for (int reg = 0; reg < 4; ++reg) {
        int grow = row0 + rg * 16 + grp * 4 + reg;
        num1[((size_t)jb * N_NODES + grow) * 32 + hg * 16 + (lane & 15)] = acc1[reg];
    }

#define DEN(KK, DD)                                                             \
    {                                                                           \
        float d = DD;                                                           \
        d += __shfl_xor(d, 1);                                                  \
        d += __shfl_xor(d, 2);                                                  \
        d += __shfl_xor(d, 4);                                                  \
        d += __shfl_xor(d, 8);                                                  \
        d += __shfl_xor(d, 16);                                                 \
        if ((tid & 31) == 0) {                                                  \
            int r = KK * 16 + trh;                                              \
            den1[(size_t)jb * N_NODES + row0 + r] = d;                          \
        }                                                                       \
    }
    DEN(0, l0)
    DEN(1, l1)
    DEN(2, l2)
    DEN(3, l3)
#undef DEN
}

// ---------------------------------------------------------------------------
// K2b3: path1 z from num1/den1; path2 z from bucket suffix scans; then
// semantic score partials. grid 1024 x 256 (8 rows x 32 h).
// ---------------------------------------------------------------------------
__global__ __launch_bounds__(256) void k2b3(
    const float* __restrict__ num1, const float* __restrict__ den1,
    const float* __restrict__ Sc,
    const float* __restrict__ s2g, const float* __restrict__ M,
    const float* __restrict__ Wsw, const float* __restrict__ Wsb,
    const float* __restrict__ bsem, const float* __restrict__ q,
    float* __restrict__ z1, float* __restrict__ z2, float* __restrict__ partial)
{
    __shared__ float zl1[256], zl2[256];
    __shared__ float rowsum[8];
    int tid = threadIdx.x;
    int row0 = blockIdx.x * 8;
    int r = tid >> 5, h = tid & 31;
    int row = row0 + r;

    // ---- path 1 ----
    float n1 = 0.f, d1 = 0.f;
#pragma unroll
    for (int jb = 0; jb < 4; ++jb) {
        n1 += num1[((size_t)jb * N_NODES + row) * 32 + h];
        d1 += den1[(size_t)jb * N_NODES + row];
    }
    float z1v = sigmoidf_(d1 > 0.f ? n1 / d1 : 0.f);

    // ---- path 2 via suffix scans ----
    float M1 = M[1], lo = M[2];
    float invw = (float)KB / fmaxf(M1 - lo, 1e-9f);
    float sv = s2g[row];
    float t = -sv;
    int bt = (int)roundf((t - lo) * invw);
    bt = min(max(bt, 0), KB);
    float u = sv + M1;
    float g1 = u >= 0.f ? 1.f : __expf(0.8f * u);
    float g2 = u >= 0.f ? __expf(-0.8f * u) : 1.f;

#define GATHER(CH, B) ((B) >= KB ? 0.f : Sc[(size_t)(CH) * KB + (B)])
    float SufE  = GATHER(h, bt);
    float SufF  = GATHER(32 + h, bt);
    float TotF  = GATHER(32 + h, 0);
    float SufEs = GATHER(64, bt);
    float SufFs = GATHER(65, bt);
    float TotFs = GATHER(65, 0);
#undef GATHER
    float num2 = g1 * SufE + g2 * (TotF - SufF);
    float den2 = g1 * SufEs + g2 * (TotFs - SufFs);
    float z2v = sigmoidf_(num2 / fmaxf(den2, 1e-30f));

    size_t gi = (size_t)row * H + h;
    z1[gi] = z1v;
    z2[gi] = z2v;
    zl1[tid] = z1v;
    zl2[tid] = z2v;
    __syncthreads();

    // ---- semantic score partials ----
    const float* wr = Wsw + h * H;
    for (int p = 0; p < 2; ++p) {
        const float* zl = p ? zl2 : zl1;
        float d = 0.f;
        const float* zr = zl + r * H;
#pragma unroll
        for (int k = 0; k < H; ++k) d += zr[k] * wr[k];
        float val = tanh_fast(d + Wsb[h] + bsem[h]) * q[h];
#pragma unroll
        for (int m = 16; m >= 1; m >>= 1) val += __shfl_xor(val, m);
        if (h == 0) rowsum[r] = val;
        __syncthreads();
        if (tid == 0) {
            float s = 0.f;
#pragma unroll
            for (int i = 0; i < 8; ++i) s += rowsum[i];
            partial[p * 1024 + blockIdx.x] = s;
        }
        __syncthreads();
    }
}

// ---------------------------------------------------------------------------
// K3b: sum partials -> beta (softmax over 2)
// ---------------------------------------------------------------------------
__global__ __launch_bounds__(256) void k3b_beta(
    const float* __restrict__ partial, float* __restrict__ beta)
{
    int tid = threadIdx.x;
    float s1 = 0.f, s2 = 0.f;
    for (int i = tid; i < 1024; i += 256) { s1 += partial[i]; s2 += partial[1024 + i]; }
#pragma unroll
    for (int m = 32; m >= 1; m >>= 1) { s1 += __shfl_xor(s1, m); s2 += __shfl_xor(s2, m); }
    __shared__ float red[8];
    if ((tid & 63) == 0) { red[(tid >> 6) * 2] = s1; red[(tid >> 6) * 2 + 1] = s2; }
    __syncthreads();
    if (tid == 0) {
        float a = red[0] + red[2] + red[4] + red[6];
        float b = red[1] + red[3] + red[5] + red[7];
        a /= (float)N_NODES;
        b /= (float)N_NODES;
        float mx = fmaxf(a, b);
        float e1 = __expf(a - mx), e2 = __expf(b - mx);
        float inv = 1.f / (e1 + e2);
        beta[0] = e1 * inv;
        beta[1] = e2 * inv;
    }
}

// ---------------------------------------------------------------------------
// K4: z_final = b0*z1 + b1*z2 ; logits = z_final @ cls_w^T + cls_b
// ---------------------------------------------------------------------------
__global__ __launch_bounds__(256) void k4_final(
    const float* __restrict__ z1, const float* __restrict__ z2,
    const float* __restrict__ beta,
    const float* __restrict__ clsw, const float* __restrict__ clsb,
    float* __restrict__ out)
{
    int tid = threadIdx.x;
    int row0 = blockIdx.x * 8;
    int r = tid >> 5, h = tid & 31;
    int grow = row0 + r;
    size_t gi = (size_t)grow * H + h;
    float b0 = beta[0], b1 = beta[1];
    float zf = b0 * z1[gi] + b1 * z2[gi];
    out[gi] = zf;
    float p0 = zf * clsw[h];
    float p1 = zf * clsw[H + h];
#pragma unroll
    for (int m = 16; m >= 1; m >>= 1) { p0 += __shfl_xor(p0, m); p1 += __shfl_xor(p1, m); }
    if (h == 0) {
        out[(size_t)N_NODES * H + (size_t)grow * 2]     = p0 + clsb[0];
        out[(size_t)N_NODES * H + (size_t)grow * 2 + 1] = p1 + clsb[1];
    }
}

extern "C" void kernel_launch(void* const* d_in, const int* in_sizes, int n_in,
                              void* d_out, int out_size, void* d_ws, size_t ws_size,
                              hipStream_t stream)
{
    const float* x    = (const float*)d_in[0];
    const float* W1   = (const float*)d_in[1];
    const float* b1   = (const float*)d_in[2];
    const float* a1   = (const float*)d_in[3];
    const float* W2   = (const float*)d_in[4];
    const float* b2   = (const float*)d_in[5];
    const float* a2   = (const float*)d_in[6];
    const float* q    = (const float*)d_in[7];
    const float* Wsw  = (const float*)d_in[8];
    const float* Wsb  = (const float*)d_in[9];
    const float* bsem = (const float*)d_in[10];
    const float* clsw = (const float*)d_in[11];
    const float* clsb = (const float*)d_in[12];
    const int*   adj  = (const int*)d_in[13];
    // d_in[14] = mg_adj : unused

    // Workspace layout in FLOAT units.
    float* ws = (float*)d_ws;
    unsigned short* WhTf = (unsigned short*)ws;        // floats [0, 131072) (bf16 frag layout)
    float* Wh2f   = ws + 131072;                       // 262144 (f32 N x H)
    float* s1     = ws + 393216;                       // 8192
    float* s2     = s1 + N_NODES;                      // 8192
    float* M      = s2 + N_NODES;                      // 8 (3 used)
    float* beta   = M + 8;                             // 8 (2 used)
    float* partial= beta + 8;                          // 2048
    float* z1     = partial + 2048;                    // 262144
    float* z2     = z1 + N_NODES * H;                  // 262144
    float* num1   = z2 + N_NODES * H;                  // 4*8192*32 = 1048576
    float* den1   = num1 + 4 * N_NODES * 32;           // 4*8192 = 32768
    float* Sc     = den1 + 4 * N_NODES;                // 66*8192 = 540672
    // total ~= 2.5M floats ~= 10 MB

    float* out = (float*)d_out;

    hipLaunchKernelGGL(k1_wh_s, dim3(1024), dim3(256), 0, stream,
                       x, W1, b1, a1, W2, b2, a2, WhTf, Wh2f, s1, s2, Sc);
    hipLaunchKernelGGL(k1b_max, dim3(1), dim3(256), 0, stream, s1, s2, M);

    // path-2 bucket pipeline
    hipLaunchKernelGGL(p2a_bucket, dim3(1024), dim3(256), 0, stream, s2, Wh2f, M, Sc);
    hipLaunchKernelGGL(p2b_scan, dim3(NCH), dim3(256), 0, stream, Sc);

    // path-1 MFMA attention
    hipLaunchKernelGGL(k2_attn1, dim3(128, 4), dim3(512), 0, stream,
                       s1, WhTf, adj, M, num1, den1);

    hipLaunchKernelGGL(k2b3, dim3(1024), dim3(256), 0, stream,
                       num1, den1, Sc, s2, M, Wsw, Wsb, bsem, q, z1, z2, partial);

    hipLaunchKernelGGL(k3b_beta, dim3(1), dim3(256), 0, stream, partial, beta);
    hipLaunchKernelGGL(k4_final, dim3(1024), dim3(256), 0, stream,
                       z1, z2, beta, clsw, clsb, out);
}